// Round 1
// baseline (134.116 us; speedup 1.0000x reference)
//
#include <hip/hip_runtime.h>

// Frames [B, T, C, H, W] = [8, 8, 3, 256, 256] fp32
#define BB 8
#define TT 8
#define NPAIR (TT - 1)               // 7
#define HH 256
#define WW 256
#define FRAME_PIX (HH * WW)
#define XW 128                       // tile width
#define RROWS 8                      // tile rows
#define NYT (HH / RROWS)             // 32
#define NXT (WW / XW)                // 2
#define PADW 136                     // 4 pad + 128 + 4 pad floats
#define NBLK (NYT * NXT * NPAIR * BB) // 3584 blocks
#define EPS 1e-3f
#define INV_N (1.0f / (float)((size_t)BB * NPAIR * 2 * HH * WW))

__device__ __forceinline__ float4 ld4(const float* __restrict__ p) {
    return *reinterpret_cast<const float4*>(p);
}
__device__ __forceinline__ void st4(float* p, const float4 v) {
    *reinterpret_cast<float4*>(p) = v;
}
__device__ __forceinline__ float4 gray4(const float4 r, const float4 g, const float4 b) {
    float4 o;
    o.x = 0.2989f * r.x + 0.587f * g.x + 0.114f * b.x;
    o.y = 0.2989f * r.y + 0.587f * g.y + 0.114f * b.y;
    o.z = 0.2989f * r.z + 0.587f * g.z + 0.114f * b.z;
    o.w = 0.2989f * r.w + 0.587f * g.w + 0.114f * b.w;
    return o;
}

// One block per (batch, pair, 128x8 tile). No temporal march: all global
// loads for frame t (with halo) and frame t+1 (center only) are issued
// up-front with no dependent chain, a single barrier covers the
// gray(t)->LDS handoff, then Sobel+flow+reduce. 3584 blocks give
// ~8 co-resident blocks/CU (32 waves) to hide HBM latency via TLP.
// Frame re-reads across neighboring pairs are absorbed by the 256MB L3.
__global__ __launch_bounds__(256, 8) void flow_loss_kernel(
    const float* __restrict__ pred, const float* __restrict__ gt,
    float* __restrict__ partial)
{
    __shared__ float gbuf[2][RROWS + 2][PADW];   // 10880 B; row 0 = y0-1

    const int ytile = blockIdx.x >> 1;
    const int xtile = blockIdx.x & 1;
    const int t     = blockIdx.y;
    const int b     = blockIdx.z;
    const int y0    = ytile * RROWS;
    const int x0    = xtile * XW;
    const int tid   = threadIdx.x;
    const size_t fs = (size_t)3 * FRAME_PIX;
    const float* p1 = pred + (size_t)b * TT * fs + (size_t)t * fs;
    const float* g1 = gt   + (size_t)b * TT * fs + (size_t)t * fs;
    const float* p2 = p1 + fs;
    const float* g2 = g1 + fs;

    // compute mapping: row r (0..7), 4 px at col cx (0..124)
    const int r  = tid >> 5;
    const int cx = (tid & 31) * 4;
    const size_t coff = (size_t)(y0 + r) * WW + (x0 + cx);

    // "extra" staging role for frame-t halo: tid<128 -> halo rows;
    // 128..167 -> side pads (both images)
    bool e_act = false, e_val = false;
    int  e_img = 0;
    size_t e_off = 0;
    float* e_dst = &gbuf[0][0][0];
    if (tid < 128) {
        e_act = true;
        e_img = tid >> 6;
        const int rsel = (tid >> 5) & 1;
        const int ec   = (tid & 31) * 4;
        const int ey   = rsel ? (y0 + RROWS) : (y0 - 1);
        e_val = (unsigned)ey < HH;
        e_off = e_val ? ((size_t)ey * WW + x0 + ec) : 0;
        e_dst = &gbuf[e_img][rsel ? RROWS + 1 : 0][4 + ec];
    } else if (tid < 168) {
        const int j = tid - 128;
        e_act = true;
        e_img = j / 20;
        const int rem  = j % 20;
        const int side = rem / 10;
        const int prow = rem % 10;
        const int ey = y0 - 1 + prow;
        const int ex = side ? (x0 + XW) : (x0 - 4);
        e_val = ((unsigned)ey < HH) && ((unsigned)ex < WW);
        e_off = e_val ? ((size_t)ey * WW + ex) : 0;
        e_dst = &gbuf[e_img][prow][side ? 4 + XW : 0];
    }

    // ---- issue ALL global loads up front (independent, deep MLP) ----
    const float4 a1r = ld4(p1 + coff);
    const float4 a1g = ld4(p1 + coff + FRAME_PIX);
    const float4 a1b = ld4(p1 + coff + 2 * FRAME_PIX);
    const float4 b1r = ld4(g1 + coff);
    const float4 b1g = ld4(g1 + coff + FRAME_PIX);
    const float4 b1b = ld4(g1 + coff + 2 * FRAME_PIX);
    const float4 a2r = ld4(p2 + coff);
    const float4 a2g = ld4(p2 + coff + FRAME_PIX);
    const float4 a2b = ld4(p2 + coff + 2 * FRAME_PIX);
    const float4 b2r = ld4(g2 + coff);
    const float4 b2g = ld4(g2 + coff + FRAME_PIX);
    const float4 b2b = ld4(g2 + coff + 2 * FRAME_PIX);
    float4 e0 = make_float4(0.f, 0.f, 0.f, 0.f), e1 = e0, e2 = e0;
    if (e_act && e_val) {
        const float* eb = e_img ? g1 : p1;
        e0 = ld4(eb + e_off);
        e1 = ld4(eb + e_off + FRAME_PIX);
        e2 = ld4(eb + e_off + 2 * FRAME_PIX);
    }

    // ---- gray(t) -> LDS (center + halo) ----
    st4(&gbuf[0][r + 1][4 + cx], gray4(a1r, a1g, a1b));
    st4(&gbuf[1][r + 1][4 + cx], gray4(b1r, b1g, b1b));
    if (e_act) st4(e_dst, gray4(e0, e1, e2));

    // motion mag for this pair (gt frames t, t+1; mean over channels)
    float mm[4];
    mm[0] = (fabsf(b2r.x - b1r.x) + fabsf(b2g.x - b1g.x) + fabsf(b2b.x - b1b.x)) * (1.f / 3.f);
    mm[1] = (fabsf(b2r.y - b1r.y) + fabsf(b2g.y - b1g.y) + fabsf(b2b.y - b1b.y)) * (1.f / 3.f);
    mm[2] = (fabsf(b2r.z - b1r.z) + fabsf(b2g.z - b1g.z) + fabsf(b2b.z - b1b.z)) * (1.f / 3.f);
    mm[3] = (fabsf(b2r.w - b1r.w) + fabsf(b2g.w - b1g.w) + fabsf(b2b.w - b1b.w)) * (1.f / 3.f);

    // gray(t+1) stays in regs (center only; It and mm need no halo)
    const float4 gp2 = gray4(a2r, a2g, a2b);
    const float4 gg2 = gray4(b2r, b2g, b2b);

    __syncthreads();

    // ---- Sobel on gray(t) from LDS, It vs gray(t+1) in regs ----
    float s = 0.f;
    float up[4], vp[4];
    #pragma unroll
    for (int img = 0; img < 2; ++img) {
        // padded floats cx+3..cx+8 -> aligned float4s at cx, cx+4, cx+8
        float w0[6], w1[6], w2[6];
        {
            const float* p = &gbuf[img][r][cx];
            const float4 A = ld4(p), B = ld4(p + 4), C = ld4(p + 8);
            w0[0] = A.w; w0[1] = B.x; w0[2] = B.y; w0[3] = B.z; w0[4] = B.w; w0[5] = C.x;
        }
        {
            const float* p = &gbuf[img][r + 1][cx];
            const float4 A = ld4(p), B = ld4(p + 4), C = ld4(p + 8);
            w1[0] = A.w; w1[1] = B.x; w1[2] = B.y; w1[3] = B.z; w1[4] = B.w; w1[5] = C.x;
        }
        {
            const float* p = &gbuf[img][r + 2][cx];
            const float4 A = ld4(p), B = ld4(p + 4), C = ld4(p + 8);
            w2[0] = A.w; w2[1] = B.x; w2[2] = B.y; w2[3] = B.z; w2[4] = B.w; w2[5] = C.x;
        }
        const float4 gr2 = img ? gg2 : gp2;
        const float g2a[4] = {gr2.x, gr2.y, gr2.z, gr2.w};
        #pragma unroll
        for (int j = 0; j < 4; ++j) {
            const float Ix = (w0[j] - w0[j + 2]) + 2.0f * (w1[j] - w1[j + 2]) + (w2[j] - w2[j + 2]);
            const float Iy = (w0[j] + 2.0f * w0[j + 1] + w0[j + 2])
                           - (w2[j] + 2.0f * w2[j + 1] + w2[j + 2]);
            const float It = g2a[j] - w1[j + 1];
            const float inv = 1.0f / (Ix * Ix + Iy * Iy + EPS);
            if (img == 0) {
                up[j] = -(Ix * It) * inv;
                vp[j] = -(Iy * It) * inv;
            } else {
                s += (fabsf(up[j] + (Ix * It) * inv) + fabsf(vp[j] + (Iy * It) * inv)) * mm[j];
            }
        }
    }

    // ---- Block reduction -> one partial per block ----
    #pragma unroll
    for (int off = 32; off > 0; off >>= 1) s += __shfl_down(s, off, 64);

    __shared__ float wsum[4];
    if ((tid & 63) == 0) wsum[tid >> 6] = s;
    __syncthreads();
    if (tid == 0) {
        partial[((b * NPAIR) + t) * (NYT * NXT) + blockIdx.x] =
            wsum[0] + wsum[1] + wsum[2] + wsum[3];
    }
}

__global__ __launch_bounds__(896) void reduce_kernel(
    const float* __restrict__ partial, float* __restrict__ out)
{
    const float4 v = ld4(partial + threadIdx.x * 4);   // 3584 floats total
    float s = (v.x + v.y) + (v.z + v.w);
    #pragma unroll
    for (int off = 32; off > 0; off >>= 1) s += __shfl_down(s, off, 64);

    __shared__ float wsum[14];
    if ((threadIdx.x & 63) == 0) wsum[threadIdx.x >> 6] = s;
    __syncthreads();
    if (threadIdx.x == 0) {
        float tot = 0.f;
        #pragma unroll
        for (int i = 0; i < 14; ++i) tot += wsum[i];
        out[0] = tot * INV_N;
    }
}

extern "C" void kernel_launch(void* const* d_in, const int* in_sizes, int n_in,
                              void* d_out, int out_size, void* d_ws, size_t ws_size,
                              hipStream_t stream) {
    const float* pred = (const float*)d_in[0];
    const float* gt   = (const float*)d_in[1];
    float* partial    = (float*)d_ws;     // NBLK floats = 14336 B
    float* out        = (float*)d_out;

    dim3 grid(NYT * NXT, NPAIR, BB);      // (64, 7, 8) = 3584 blocks
    dim3 block(256);
    flow_loss_kernel<<<grid, block, 0, stream>>>(pred, gt, partial);
    reduce_kernel<<<1, 896, 0, stream>>>(partial, out);
}

// Round 2
// 119.216 us; speedup vs baseline: 1.1250x; 1.1250x over previous
//
#include <hip/hip_runtime.h>

// Frames [B, T, C, H, W] = [8, 8, 3, 256, 256] fp32
#define BB 8
#define TT 8
#define NPAIR (TT - 1)               // 7
#define HH 256
#define WW 256
#define FRAME_PIX (HH * WW)
#define XW 128                       // tile width
#define RROWS 8                      // tile rows
#define NYT (HH / RROWS)             // 32
#define NXT (WW / XW)                // 2
#define PADW 136                     // 4 pad + 128 + 4 pad floats
#define NBLK (NYT * NXT * NPAIR * BB) // 3584 blocks
#define EPS 1e-3f
#define INV_N (1.0f / (float)((size_t)BB * NPAIR * 2 * HH * WW))

__device__ __forceinline__ float4 ld4(const float* __restrict__ p) {
    return *reinterpret_cast<const float4*>(p);
}
__device__ __forceinline__ void st4(float* p, const float4 v) {
    *reinterpret_cast<float4*>(p) = v;
}
__device__ __forceinline__ float4 gray4(const float4 r, const float4 g, const float4 b) {
    float4 o;
    o.x = 0.2989f * r.x + 0.587f * g.x + 0.114f * b.x;
    o.y = 0.2989f * r.y + 0.587f * g.y + 0.114f * b.y;
    o.z = 0.2989f * r.z + 0.587f * g.z + 0.114f * b.z;
    o.w = 0.2989f * r.w + 0.587f * g.w + 0.114f * b.w;
    return o;
}

// One block per (batch, pair, 128x8 tile). All global loads issued up-front
// with no dependent chain; single barrier for the gray(t)->LDS handoff.
// __launch_bounds__(256, 3): VGPR cap ~168 so the ~15 in-flight float4
// loads (60 VGPRs of destinations) are NOT spilled to scratch (the
// (256,8)/32-VGPR variant spilled ~10 dwords/thread -> 36MB scratch
// writes and no speedup). 3 blocks/CU x 60KB outstanding loads >> the
// ~22KB/CU needed to saturate HBM at ~900cy latency.
__global__ __launch_bounds__(256, 3) void flow_loss_kernel(
    const float* __restrict__ pred, const float* __restrict__ gt,
    float* __restrict__ partial)
{
    __shared__ float gbuf[2][RROWS + 2][PADW];   // 10880 B; row 0 = y0-1

    const int ytile = blockIdx.x >> 1;
    const int xtile = blockIdx.x & 1;
    const int t     = blockIdx.y;
    const int b     = blockIdx.z;
    const int y0    = ytile * RROWS;
    const int x0    = xtile * XW;
    const int tid   = threadIdx.x;
    const size_t fs = (size_t)3 * FRAME_PIX;
    const float* p1 = pred + (size_t)b * TT * fs + (size_t)t * fs;
    const float* g1 = gt   + (size_t)b * TT * fs + (size_t)t * fs;
    const float* p2 = p1 + fs;
    const float* g2 = g1 + fs;

    // compute mapping: row r (0..7), 4 px at col cx (0..124)
    const int r  = tid >> 5;
    const int cx = (tid & 31) * 4;
    const size_t coff = (size_t)(y0 + r) * WW + (x0 + cx);

    // "extra" staging role for frame-t halo: tid<128 -> halo rows;
    // 128..167 -> side pads (both images)
    bool e_act = false, e_val = false;
    int  e_img = 0;
    size_t e_off = 0;
    float* e_dst = &gbuf[0][0][0];
    if (tid < 128) {
        e_act = true;
        e_img = tid >> 6;
        const int rsel = (tid >> 5) & 1;
        const int ec   = (tid & 31) * 4;
        const int ey   = rsel ? (y0 + RROWS) : (y0 - 1);
        e_val = (unsigned)ey < HH;
        e_off = e_val ? ((size_t)ey * WW + x0 + ec) : 0;
        e_dst = &gbuf[e_img][rsel ? RROWS + 1 : 0][4 + ec];
    } else if (tid < 168) {
        const int j = tid - 128;
        e_act = true;
        e_img = j / 20;
        const int rem  = j % 20;
        const int side = rem / 10;
        const int prow = rem % 10;
        const int ey = y0 - 1 + prow;
        const int ex = side ? (x0 + XW) : (x0 - 4);
        e_val = ((unsigned)ey < HH) && ((unsigned)ex < WW);
        e_off = e_val ? ((size_t)ey * WW + ex) : 0;
        e_dst = &gbuf[e_img][prow][side ? 4 + XW : 0];
    }

    // ---- issue ALL global loads up front (independent, deep MLP) ----
    const float4 a1r = ld4(p1 + coff);
    const float4 a1g = ld4(p1 + coff + FRAME_PIX);
    const float4 a1b = ld4(p1 + coff + 2 * FRAME_PIX);
    const float4 b1r = ld4(g1 + coff);
    const float4 b1g = ld4(g1 + coff + FRAME_PIX);
    const float4 b1b = ld4(g1 + coff + 2 * FRAME_PIX);
    const float4 a2r = ld4(p2 + coff);
    const float4 a2g = ld4(p2 + coff + FRAME_PIX);
    const float4 a2b = ld4(p2 + coff + 2 * FRAME_PIX);
    const float4 b2r = ld4(g2 + coff);
    const float4 b2g = ld4(g2 + coff + FRAME_PIX);
    const float4 b2b = ld4(g2 + coff + 2 * FRAME_PIX);
    float4 e0 = make_float4(0.f, 0.f, 0.f, 0.f), e1 = e0, e2 = e0;
    if (e_act && e_val) {
        const float* eb = e_img ? g1 : p1;
        e0 = ld4(eb + e_off);
        e1 = ld4(eb + e_off + FRAME_PIX);
        e2 = ld4(eb + e_off + 2 * FRAME_PIX);
    }

    // ---- gray(t) -> LDS (center + halo) ----
    st4(&gbuf[0][r + 1][4 + cx], gray4(a1r, a1g, a1b));
    st4(&gbuf[1][r + 1][4 + cx], gray4(b1r, b1g, b1b));
    if (e_act) st4(e_dst, gray4(e0, e1, e2));

    // motion mag for this pair (gt frames t, t+1; mean over channels)
    float mm[4];
    mm[0] = (fabsf(b2r.x - b1r.x) + fabsf(b2g.x - b1g.x) + fabsf(b2b.x - b1b.x)) * (1.f / 3.f);
    mm[1] = (fabsf(b2r.y - b1r.y) + fabsf(b2g.y - b1g.y) + fabsf(b2b.y - b1b.y)) * (1.f / 3.f);
    mm[2] = (fabsf(b2r.z - b1r.z) + fabsf(b2g.z - b1g.z) + fabsf(b2b.z - b1b.z)) * (1.f / 3.f);
    mm[3] = (fabsf(b2r.w - b1r.w) + fabsf(b2g.w - b1g.w) + fabsf(b2b.w - b1b.w)) * (1.f / 3.f);

    // gray(t+1) stays in regs (center only; It and mm need no halo)
    const float4 gp2 = gray4(a2r, a2g, a2b);
    const float4 gg2 = gray4(b2r, b2g, b2b);

    __syncthreads();

    // ---- Sobel on gray(t) from LDS, It vs gray(t+1) in regs ----
    float s = 0.f;
    float up[4], vp[4];
    #pragma unroll
    for (int img = 0; img < 2; ++img) {
        // padded floats cx+3..cx+8 -> aligned float4s at cx, cx+4, cx+8
        float w0[6], w1[6], w2[6];
        {
            const float* p = &gbuf[img][r][cx];
            const float4 A = ld4(p), B = ld4(p + 4), C = ld4(p + 8);
            w0[0] = A.w; w0[1] = B.x; w0[2] = B.y; w0[3] = B.z; w0[4] = B.w; w0[5] = C.x;
        }
        {
            const float* p = &gbuf[img][r + 1][cx];
            const float4 A = ld4(p), B = ld4(p + 4), C = ld4(p + 8);
            w1[0] = A.w; w1[1] = B.x; w1[2] = B.y; w1[3] = B.z; w1[4] = B.w; w1[5] = C.x;
        }
        {
            const float* p = &gbuf[img][r + 2][cx];
            const float4 A = ld4(p), B = ld4(p + 4), C = ld4(p + 8);
            w2[0] = A.w; w2[1] = B.x; w2[2] = B.y; w2[3] = B.z; w2[4] = B.w; w2[5] = C.x;
        }
        const float4 gr2 = img ? gg2 : gp2;
        const float g2a[4] = {gr2.x, gr2.y, gr2.z, gr2.w};
        #pragma unroll
        for (int j = 0; j < 4; ++j) {
            const float Ix = (w0[j] - w0[j + 2]) + 2.0f * (w1[j] - w1[j + 2]) + (w2[j] - w2[j + 2]);
            const float Iy = (w0[j] + 2.0f * w0[j + 1] + w0[j + 2])
                           - (w2[j] + 2.0f * w2[j + 1] + w2[j + 2]);
            const float It = g2a[j] - w1[j + 1];
            const float inv = 1.0f / (Ix * Ix + Iy * Iy + EPS);
            if (img == 0) {
                up[j] = -(Ix * It) * inv;
                vp[j] = -(Iy * It) * inv;
            } else {
                s += (fabsf(up[j] + (Ix * It) * inv) + fabsf(vp[j] + (Iy * It) * inv)) * mm[j];
            }
        }
    }

    // ---- Block reduction -> one partial per block ----
    #pragma unroll
    for (int off = 32; off > 0; off >>= 1) s += __shfl_down(s, off, 64);

    __shared__ float wsum[4];
    if ((tid & 63) == 0) wsum[tid >> 6] = s;
    __syncthreads();
    if (tid == 0) {
        partial[((b * NPAIR) + t) * (NYT * NXT) + blockIdx.x] =
            wsum[0] + wsum[1] + wsum[2] + wsum[3];
    }
}

__global__ __launch_bounds__(896) void reduce_kernel(
    const float* __restrict__ partial, float* __restrict__ out)
{
    const float4 v = ld4(partial + threadIdx.x * 4);   // 3584 floats total
    float s = (v.x + v.y) + (v.z + v.w);
    #pragma unroll
    for (int off = 32; off > 0; off >>= 1) s += __shfl_down(s, off, 64);

    __shared__ float wsum[14];
    if ((threadIdx.x & 63) == 0) wsum[threadIdx.x >> 6] = s;
    __syncthreads();
    if (threadIdx.x == 0) {
        float tot = 0.f;
        #pragma unroll
        for (int i = 0; i < 14; ++i) tot += wsum[i];
        out[0] = tot * INV_N;
    }
}

extern "C" void kernel_launch(void* const* d_in, const int* in_sizes, int n_in,
                              void* d_out, int out_size, void* d_ws, size_t ws_size,
                              hipStream_t stream) {
    const float* pred = (const float*)d_in[0];
    const float* gt   = (const float*)d_in[1];
    float* partial    = (float*)d_ws;     // NBLK floats = 14336 B
    float* out        = (float*)d_out;

    dim3 grid(NYT * NXT, NPAIR, BB);      // (64, 7, 8) = 3584 blocks
    dim3 block(256);
    flow_loss_kernel<<<grid, block, 0, stream>>>(pred, gt, partial);
    reduce_kernel<<<1, 896, 0, stream>>>(partial, out);
}